// Round 16
// baseline (5271.434 us; speedup 1.0000x reference)
//
#include <hip/hip_runtime.h>

#define NB 36
#define NT 60

typedef __attribute__((ext_vector_type(8))) short short8;
typedef __attribute__((ext_vector_type(4))) float f32x4;

struct Params {
  const float *data;
  const float *W0, *b0, *W1, *b1, *W2, *b2, *Wf1, *bf1, *Wf2, *bf2;
  float *xb, *w0t;
  unsigned short *w1h, *w1l, *w2h, *w2l;
  unsigned int *xhl, *p1hl;
  float *outp2, *u1s;
  float *dm0, *dm1, *dmp1, *dm2, *dmp2, *dmh1, *dmh2;
  float *acc;
  float *zbase; int zn4;
};

__device__ __forceinline__ unsigned short bf16_rne(float v){
  unsigned int bits = __float_as_uint(v);
  unsigned int r = bits + 0x7FFFu + ((bits >> 16) & 1u);
  return (unsigned short)(r >> 16);
}
__device__ __forceinline__ unsigned int bf16pack(float v){
  unsigned short h = bf16_rne(v);
  float hf = __uint_as_float((unsigned int)h << 16);
  unsigned short l = bf16_rne(v - hf);
  return (unsigned int)h | ((unsigned int)l << 16);
}
__device__ __forceinline__ void unpack8(const unsigned int* q, short8& h8, short8& l8){
  unsigned int u[8];
  *(uint4*)&u[0] = *(const uint4*)q;
  *(uint4*)&u[4] = *(const uint4*)(q+4);
  #pragma unroll
  for(int i=0;i<8;i++){
    h8[i] = (short)(u[i] & 0xffffu);
    l8[i] = (short)(u[i] >> 16);
  }
}

// ---------------- prep ----------------
// xb fill: one (bc,pixel) per thread, t innermost (R13-verified: FETCH 179->10MB).
__global__ void __launch_bounds__(256) k_prep(Params p){
  int gt  = blockIdx.x*256 + threadIdx.x;
  int STR = gridDim.x*256;
  if(gt < NB*11) p.acc[gt] = 0.f;
  for(int i=gt; i<p.zn4; i+=STR) ((float4*)p.zbase)[i] = make_float4(0.f,0.f,0.f,0.f);
  const int PLANE = 34*34;
  for(int i=gt; i<NB*2*PLANE; i+=STR){
    int bc  = i / PLANE;
    int pix = i % PLANE;
    int ph = pix/34, pw = pix%34;
    float* xp = p.xb + (size_t)bc*PLANE + pix;
    if(ph>=1 && ph<=32 && pw>=1 && pw<=32){
      const float* dp = p.data + ((size_t)bc*1024 + (ph-1)*32 + (pw-1))*NT;
      for(int t=0;t<NT;t++)
        xp[(size_t)t*NB*2*PLANE] = (dp[t] > 1.0f) ? 1.0f : 0.0f;
    } else {
      for(int t=0;t<NT;t++)
        xp[(size_t)t*NB*2*PLANE] = 0.f;
    }
  }
  for(int i=gt; i<2*9*64; i+=STR){
    int co=i%64, rr=i/64; p.w0t[i] = p.W0[(co*2 + rr/9)*9 + rr%9];
  }
  // w1 split (RNE), layout [cout][k=cin*9+dd], K=576
  for(int i=gt; i<128*576; i+=STR){
    int co = i/576, k = i%576;
    int cin = k/9, dd = k%9;
    unsigned int pk = bf16pack(p.W1[(co*64+cin)*9 + dd]);
    p.w1h[i]=(unsigned short)(pk&0xffffu); p.w1l[i]=(unsigned short)(pk>>16);
  }
  // w2 split (RNE), layout [cout][k=cin*9+dd], K=1152
  for(int i=gt; i<128*1152; i+=STR){
    int co = i/1152, k = i%1152;
    int cin = k/9, dd = k%9;
    unsigned int pk = bf16pack(p.W2[(co*128+cin)*9 + dd]);
    p.w2h[i]=(unsigned short)(pk&0xffffu); p.w2l[i]=(unsigned short)(pk>>16);
  }
}

// ---------------- conv0 standalone (prologue t=0 only) ----------------
template<int Cin,int Cout,int HW,int CO,int PX,int TY,int CS>
__global__ void __launch_bounds__(HW*TY)
k_conv0(const float* __restrict__ x, const float* __restrict__ wt,
        const float* __restrict__ bias, float* __restrict__ dm,
        unsigned int* __restrict__ outhl)
{
  const int NCOG = Cout/CO;
  const int TH   = PX*TY;
  const int NHG  = HW/TH;
  const int NH4  = CO/4;
  const int NTHL = HW*TY;
  const int PIN  = HW+2;
  const int XR   = PX+2;
  int tile = blockIdx.x;
  int tid  = threadIdx.x;
  int cog = tile % NCOG;
  int hg  = (tile/NCOG) % NHG;
  int b   = tile/(NCOG*NHG);
  int w0  = tid % HW;
  int ty  = tid / HW;
  int h0  = hg*TH + ty*PX;

  __shared__ __align__(16) float wl[CS*9*CO];

  float accs[PX][CO];
  #pragma unroll
  for(int p=0;p<PX;p++)
    #pragma unroll
    for(int c=0;c<CO;c++) accs[p][c]=0.f;

  for(int cs=0; cs<Cin; cs+=CS){
    __syncthreads();
    for(int j=tid; j<CS*9*CO; j+=NTHL){
      int c  = j % CO;
      int rr = j / CO;
      wl[j] = wt[(cs*9 + rr)*Cout + cog*CO + c];
    }
    __syncthreads();

    for(int lc=0; lc<CS; lc++){
      const float* xc = x + ((size_t)b*Cin + cs + lc)*PIN*PIN + (size_t)h0*PIN + w0;
      float xv[XR][3];
      #pragma unroll
      for(int r=0;r<XR;r++)
        #pragma unroll
        for(int c=0;c<3;c++) xv[r][c] = xc[(size_t)r*PIN + c];
      const float4* w4 = (const float4*)(wl + lc*9*CO);
      #pragma unroll
      for(int dh=0;dh<3;dh++){
        #pragma unroll
        for(int g=0;g<NH4;g++){
          float4 wa = w4[(dh*3+0)*NH4+g];
          float4 wb = w4[(dh*3+1)*NH4+g];
          float4 wc = w4[(dh*3+2)*NH4+g];
          const float* A  = (const float*)&wa;
          const float* Bp = (const float*)&wb;
          const float* Cp = (const float*)&wc;
          #pragma unroll
          for(int cc=0;cc<4;cc++){
            #pragma unroll
            for(int px=0;px<PX;px++)
              accs[px][g*4+cc] += A[cc]*xv[px+dh][0] + Bp[cc]*xv[px+dh][1] + Cp[cc]*xv[px+dh][2];
          }
        }
      }
    }
  }

  int co0 = cog*CO;
  #pragma unroll
  for(int co=0; co<CO; co++){
    float bsv = bias[co0+co];
    const int OS = HW + 2;
    size_t plane = (size_t)(b*Cout + co0+co)*OS*OS;
    #pragma unroll
    for(int px=0; px<PX; px++){
      size_t idx = plane + (size_t)(h0+px+1)*OS + w0 + 1;
      float mem = dm[idx] + accs[px][co] + bsv;
      float ov = mem > 0.f ? mem : 0.f;
      dm[idx]  = (mem > 0.5f) ? 0.f : 0.3f*mem;
      outhl[idx] = bf16pack(ov);
    }
  }
}

// ---------------- conv1: implicit-GEMM MFMA bf16x3 + LIAF + pool -> packed bf16 ----------------
// R14-verified: BK=64 (9 double-chunks, 18 barriers). LDS 37.9KB, VGPR 52, 4 blocks/CU.
__global__ void __launch_bounds__(256, 4)
k_conv1(const unsigned int* __restrict__ xhl,
        const unsigned short* __restrict__ w1h, const unsigned short* __restrict__ w1l,
        const float* __restrict__ bias, float* __restrict__ dm,
        float* __restrict__ dmp, unsigned int* __restrict__ p1hl)
{
  __shared__ __align__(16) unsigned int ldsu[9472];    // 37.9 KB
  unsigned short* Ah = (unsigned short*)ldsu;          // 64*72 ushorts
  unsigned short* Al = (unsigned short*)(ldsu + 2304);
  unsigned int*   Xp = ldsu + 4608;                    // 64*76 uints

  int bid = blockIdx.x;
  int cog = bid & 1;
  int pxg = (bid>>1) & 15;
  int b   = bid >> 5;
  int tid = threadIdx.x;
  int wv  = tid >> 6, lane = tid & 63;
  int wm = wv & 1, wn = wv >> 1;
  int n = lane & 15, quad = lane >> 4;
  int r0 = pxg*2;

  f32x4 acc[2][2];
  #pragma unroll
  for(int mo=0;mo<2;mo++)
    #pragma unroll
    for(int no=0;no<2;no++) acc[mo][no] = (f32x4){0.f,0.f,0.f,0.f};

  int aco = tid >> 2;
  int aq  = tid & 3;
  const unsigned short* whp = w1h + (size_t)(cog*64 + aco)*576 + aq*8;
  const unsigned short* wlp = w1l + (size_t)(cog*64 + aco)*576 + aq*8;
  int sk  = tid >> 3;
  int pxq = tid & 7;
  int srow = pxq >> 2;
  int scol = (pxq & 3) * 8;
  int rA   = pxq * 8;
  int skx  = sk ^ (((pxq >> 1) & 3) << 3);

  // ---- prologue: prefetch chunk 0, both k-halves (contiguous -> dwordx4) ----
  uint4 whaA = *(const uint4*)(whp);
  uint4 whaB = *(const uint4*)(whp + 32);
  uint4 wlaA = *(const uint4*)(wlp);
  uint4 wlaB = *(const uint4*)(wlp + 32);
  unsigned int tmp[16];
  {
    int kg0 = sk,      cin0 = kg0/9, dd0 = kg0 - cin0*9, dh0 = dd0/3, dw0 = dd0 - dh0*3;
    int kg1 = sk + 32, cin1 = kg1/9, dd1 = kg1 - cin1*9, dh1 = dd1/3, dw1 = dd1 - dh1*3;
    const unsigned int* s0 = xhl + ((size_t)(b*64 + cin0)*34 + (r0 + srow + dh0))*34 + scol + dw0;
    const unsigned int* s1 = xhl + ((size_t)(b*64 + cin1)*34 + (r0 + srow + dh1))*34 + scol + dw1;
    #pragma unroll
    for(int i=0;i<8;i++){ tmp[i] = s0[i]; tmp[8+i] = s1[i]; }
  }

  for(int ch=0; ch<9; ch++){
    __syncthreads();
    *(uint4*)&Ah[aco*72 + aq*8]      = whaA;
    *(uint4*)&Ah[aco*72 + aq*8 + 32] = whaB;
    *(uint4*)&Al[aco*72 + aq*8]      = wlaA;
    *(uint4*)&Al[aco*72 + aq*8 + 32] = wlaB;
    #pragma unroll
    for(int i=0;i<8;i++){
      Xp[(rA+i)*76 + skx]      = tmp[i];
      Xp[(rA+i)*76 + skx + 32] = tmp[8+i];
    }
    __syncthreads();

    // ---- prefetch next double-chunk during compute ----
    if(ch+1 < 9){
      int k0n = (ch+1)*64;
      whaA = *(const uint4*)(whp + k0n);
      whaB = *(const uint4*)(whp + k0n + 32);
      wlaA = *(const uint4*)(wlp + k0n);
      wlaB = *(const uint4*)(wlp + k0n + 32);
      int kg0 = k0n + sk,      cin0 = kg0/9, dd0 = kg0 - cin0*9, dh0 = dd0/3, dw0 = dd0 - dh0*3;
      int kg1 = k0n + sk + 32, cin1 = kg1/9, dd1 = kg1 - cin1*9, dh1 = dd1/3, dw1 = dd1 - dh1*3;
      const unsigned int* s0 = xhl + ((size_t)(b*64 + cin0)*34 + (r0 + srow + dh0))*34 + scol + dw0;
      const unsigned int* s1 = xhl + ((size_t)(b*64 + cin1)*34 + (r0 + srow + dh1))*34 + scol + dw1;
      #pragma unroll
      for(int i=0;i<8;i++){ tmp[i] = s0[i]; tmp[8+i] = s1[i]; }
    }

    #pragma unroll
    for(int kk=0; kk<2; kk++){
      int ko = kk*32;
      short8 ahf[2], alf[2];
      #pragma unroll
      for(int mo=0;mo<2;mo++){
        int row = wm*32 + mo*16 + n;
        ahf[mo] = *(const short8*)&Ah[row*72 + ko + quad*8];
        alf[mo] = *(const short8*)&Al[row*72 + ko + quad*8];
      }
      #pragma unroll
      for(int no=0;no<2;no++){
        int prow = no*32 + wn*16 + n;
        int cb = ((quad ^ (no*2 + wn)) & 3) * 8;
        short8 xhf, xlf;
        unpack8(&Xp[prow*76 + ko + cb], xhf, xlf);
        #pragma unroll
        for(int mo=0;mo<2;mo++){
          acc[mo][no] = __builtin_amdgcn_mfma_f32_16x16x32_bf16(ahf[mo], xhf, acc[mo][no],0,0,0);
          acc[mo][no] = __builtin_amdgcn_mfma_f32_16x16x32_bf16(ahf[mo], xlf, acc[mo][no],0,0,0);
          acc[mo][no] = __builtin_amdgcn_mfma_f32_16x16x32_bf16(alf[mo], xhf, acc[mo][no],0,0,0);
        }
      }
    }
  }

  // epilogue: LIAF (dm1 32x32) + 2x2 pool -> packed bf16 (18x18 padded)
  #pragma unroll
  for(int mo=0;mo<2;mo++){
    #pragma unroll
    for(int reg=0;reg<4;reg++){
      int co = cog*64 + wm*32 + mo*16 + quad*4 + reg;
      float bsv = bias[co];
      float o[2];
      #pragma unroll
      for(int no=0;no<2;no++){
        int r = r0 + no;
        int c = wn*16 + n;
        size_t idx = (((size_t)b*128 + co)*32 + r)*32 + c;
        float mem = dm[idx] + acc[mo][no][reg] + bsv;
        o[no] = mem > 0.f ? mem : 0.f;
        dm[idx] = (mem > 0.5f) ? 0.f : 0.3f*mem;
      }
      float s = o[0] + o[1];
      s += __shfl_xor(s, 1, 64);
      if((n&1)==0){
        int pr = pxg;
        int pc = wn*8 + (n>>1);
        size_t pidx = (((size_t)b*128 + co)*18 + pr+1)*18 + pc+1;
        float pm = dmp[pidx] + s*0.25f;
        float pv = pm > 0.f ? pm : 0.f;
        dmp[pidx] = (pm > 0.5f) ? 0.f : 0.3f*pm;
        p1hl[pidx] = bf16pack(pv);
      }
    }
  }
}

// ---------------- X2: conv2(t) [0..575] + conv0(t+1) [576..863] + fc2(t-1) [864..899] ----
// THIS ROUND: conv2 goes BK=64 (18 double-chunks, 36 barriers vs 72 — the R14-verified
// transformation). Ah/Al 64x72 ushorts, Xp 32x76 uints; LDS 28.2KB (>=4 blocks/CU at 256,4).
// Pitch 76 = 44 (mod 32), XOR untouched bit 5 -> verified bank pattern in both k-halves;
// accumulation order bit-identical (k-block 2CH, 2CH+1). conv0/fc2 branches unchanged.
__global__ void __launch_bounds__(256, 4)
k_x2(const unsigned int* __restrict__ p1hl,
     const unsigned short* __restrict__ w2h, const unsigned short* __restrict__ w2l,
     const float* __restrict__ bias2, float* __restrict__ dm2,
     float* __restrict__ dmp2, float* __restrict__ outp,
     const float* __restrict__ xnext, const float* __restrict__ w0t,
     const float* __restrict__ bias0, float* __restrict__ dm0,
     unsigned int* __restrict__ xhl, int do_c0,
     const float* __restrict__ u1s, const float* __restrict__ bf1,
     const float* __restrict__ Wf2, const float* __restrict__ bf2,
     float* __restrict__ dmh1, float* __restrict__ dmh2,
     float* __restrict__ accv, int do_fc2)
{
  __shared__ __align__(16) unsigned int ldsu[7040];    // 28.2 KB
  const int tid = threadIdx.x;
  int bid = blockIdx.x;

  if(bid >= 864){
    // ---------- fc2(t-1) ----------
    if(!do_fc2) return;
    float* xs = (float*)ldsu;
    int b = bid - 864;
    int o = tid;
    float u = bf1[o];
    const float* pu = u1s + (size_t)b*256 + o;
    #pragma unroll
    for(int s=0;s<32;s++) u += pu[(size_t)s*NB*256];
    int idx = b*256 + o;
    float mem = dmh1[idx] + u;
    float xo = mem > 0.f ? mem : 0.f;
    dmh1[idx] = (mem > 0.5f) ? 0.f : 0.3f*mem;
    xs[o] = xo;
    __syncthreads();
    int w_id = o >> 6, ln = o & 63;
    for(int oo=w_id; oo<11; oo+=4){
      const float* wr = Wf2 + oo*256;
      float s = xs[ln]*wr[ln] + xs[ln+64]*wr[ln+64]
              + xs[ln+128]*wr[ln+128] + xs[ln+192]*wr[ln+192];
      #pragma unroll
      for(int off=32; off>0; off>>=1) s += __shfl_down(s, off, 64);
      if(ln==0){
        int i2 = b*11 + oo;
        float m2 = dmh2[i2] + s + bf2[oo];
        float ov = m2 > 0.f ? m2 : 0.f;
        dmh2[i2] = (m2 > 0.5f) ? 0.f : 0.3f*m2;
        accv[i2] += ov * (1.0f/60.0f);
      }
    }
    return;
  }

  if(bid >= 576){
    // ---------- conv0(t+1) ----------
    if(!do_c0) return;
    float* wl = (float*)ldsu;      // 144 floats
    int tile = bid - 576;
    int cog = tile & 7;
    int b   = tile >> 3;
    int w0  = tid & 31;
    int ty  = tid >> 5;
    int h0  = ty*4;

    float accs[4][8];
    #pragma unroll
    for(int p=0;p<4;p++)
      #pragma unroll
      for(int c=0;c<8;c++) accs[p][c]=0.f;

    if(tid < 144){
      int c  = tid % 8;
      int rr = tid / 8;
      wl[tid] = w0t[rr*64 + cog*8 + c];
    }
    __syncthreads();

    #pragma unroll
    for(int lc=0; lc<2; lc++){
      const float* xc = xnext + ((size_t)b*2 + lc)*34*34 + (size_t)h0*34 + w0;
      float xv[6][3];
      #pragma unroll
      for(int r=0;r<6;r++)
        #pragma unroll
        for(int c=0;c<3;c++) xv[r][c] = xc[(size_t)r*34 + c];
      const float4* w4 = (const float4*)(wl + lc*72);
      #pragma unroll
      for(int dh=0;dh<3;dh++){
        #pragma unroll
        for(int g=0;g<2;g++){
          float4 wa = w4[(dh*3+0)*2+g];
          float4 wb = w4[(dh*3+1)*2+g];
          float4 wc = w4[(dh*3+2)*2+g];
          const float* A  = (const float*)&wa;
          const float* Bp = (const float*)&wb;
          const float* Cp = (const float*)&wc;
          #pragma unroll
          for(int cc=0;cc<4;cc++){
            #pragma unroll
            for(int px=0;px<4;px++)
              accs[px][g*4+cc] += A[cc]*xv[px+dh][0] + Bp[cc]*xv[px+dh][1] + Cp[cc]*xv[px+dh][2];
          }
        }
      }
    }

    int co0 = cog*8;
    #pragma unroll
    for(int co=0; co<8; co++){
      float bsv = bias0[co0+co];
      size_t plane = (size_t)(b*64 + co0+co)*34*34;
      #pragma unroll
      for(int px=0; px<4; px++){
        size_t idx = plane + (size_t)(h0+px+1)*34 + w0 + 1;
        float mem = dm0[idx] + accs[px][co] + bsv;
        float ov = mem > 0.f ? mem : 0.f;
        dm0[idx]  = (mem > 0.5f) ? 0.f : 0.3f*mem;
        xhl[idx] = bf16pack(ov);
      }
    }
    return;
  }

  // ---------- conv2(t), BK=64 ----------
  unsigned short* Ah = (unsigned short*)ldsu;          // 64*72 ushorts
  unsigned short* Al = (unsigned short*)(ldsu + 2304);
  unsigned int*   Xp = ldsu + 4608;                    // 32*76 uints

  int cog = bid & 1;
  int pxg = (bid>>1) & 7;
  int b   = bid >> 4;
  int wv  = tid >> 6, lane = tid & 63;
  int wm = wv & 1, wn = wv >> 1;
  int n = lane & 15, quad = lane >> 4;
  int r0 = pxg*2;

  f32x4 acc2[2];
  #pragma unroll
  for(int mo=0;mo<2;mo++) acc2[mo] = (f32x4){0.f,0.f,0.f,0.f};

  int aco = tid >> 2;
  int aq  = tid & 3;
  const unsigned short* whp = w2h + (size_t)(cog*64 + aco)*1152 + aq*8;
  const unsigned short* wlp = w2l + (size_t)(cog*64 + aco)*1152 + aq*8;
  int sk  = tid >> 3;
  int pxq = tid & 7;
  int srow = pxq >> 2;
  int scol = (pxq & 3) * 4;
  int rA   = pxq * 4;
  int skx  = sk ^ ((pxq >> 2) << 3);

  // ---- prologue: prefetch chunk 0, both k-halves ----
  uint4 whaA = *(const uint4*)(whp);
  uint4 whaB = *(const uint4*)(whp + 32);
  uint4 wlaA = *(const uint4*)(wlp);
  uint4 wlaB = *(const uint4*)(wlp + 32);
  unsigned int tmp[8];
  {
    int kg0 = sk,      cin0 = kg0/9, dd0 = kg0 - cin0*9, dh0 = dd0/3, dw0 = dd0 - dh0*3;
    int kg1 = sk + 32, cin1 = kg1/9, dd1 = kg1 - cin1*9, dh1 = dd1/3, dw1 = dd1 - dh1*3;
    const unsigned int* s0 = p1hl + ((size_t)(b*128 + cin0)*18 + (r0 + srow + dh0))*18 + scol + dw0;
    const unsigned int* s1 = p1hl + ((size_t)(b*128 + cin1)*18 + (r0 + srow + dh1))*18 + scol + dw1;
    #pragma unroll
    for(int i=0;i<4;i++){ tmp[i] = s0[i]; tmp[4+i] = s1[i]; }
  }

  for(int ch=0; ch<18; ch++){
    __syncthreads();
    *(uint4*)&Ah[aco*72 + aq*8]      = whaA;
    *(uint4*)&Ah[aco*72 + aq*8 + 32] = whaB;
    *(uint4*)&Al[aco*72 + aq*8]      = wlaA;
    *(uint4*)&Al[aco*72 + aq*8 + 32] = wlaB;
    #pragma unroll
    for(int i=0;i<4;i++){
      Xp[(rA+i)*76 + skx]      = tmp[i];
      Xp[(rA+i)*76 + skx + 32] = tmp[4+i];
    }
    __syncthreads();

    // ---- prefetch next double-chunk during compute ----
    if(ch+1 < 18){
      int k0n = (ch+1)*64;
      whaA = *(const uint4*)(whp + k0n);
      whaB = *(const uint4*)(whp + k0n + 32);
      wlaA = *(const uint4*)(wlp + k0n);
      wlaB = *(const uint4*)(wlp + k0n + 32);
      int kg0 = k0n + sk,      cin0 = kg0/9, dd0 = kg0 - cin0*9, dh0 = dd0/3, dw0 = dd0 - dh0*3;
      int kg1 = k0n + sk + 32, cin1 = kg1/9, dd1 = kg1 - cin1*9, dh1 = dd1/3, dw1 = dd1 - dh1*3;
      const unsigned int* s0 = p1hl + ((size_t)(b*128 + cin0)*18 + (r0 + srow + dh0))*18 + scol + dw0;
      const unsigned int* s1 = p1hl + ((size_t)(b*128 + cin1)*18 + (r0 + srow + dh1))*18 + scol + dw1;
      #pragma unroll
      for(int i=0;i<4;i++){ tmp[i] = s0[i]; tmp[4+i] = s1[i]; }
    }

    #pragma unroll
    for(int kk=0; kk<2; kk++){
      int ko = kk*32;
      short8 ahf[2], alf[2];
      #pragma unroll
      for(int mo=0;mo<2;mo++){
        int row = wm*32 + mo*16 + n;
        ahf[mo] = *(const short8*)&Ah[row*72 + ko + quad*8];
        alf[mo] = *(const short8*)&Al[row*72 + ko + quad*8];
      }
      {
        int prow = (n>>3)*16 + wn*8 + (n&7);
        int cb = ((quad ^ (n>>3)) & 3) * 8;
        short8 xhf, xlf;
        unpack8(&Xp[prow*76 + ko + cb], xhf, xlf);
        #pragma unroll
        for(int mo=0;mo<2;mo++){
          acc2[mo] = __builtin_amdgcn_mfma_f32_16x16x32_bf16(ahf[mo], xhf, acc2[mo],0,0,0);
          acc2[mo] = __builtin_amdgcn_mfma_f32_16x16x32_bf16(ahf[mo], xlf, acc2[mo],0,0,0);
          acc2[mo] = __builtin_amdgcn_mfma_f32_16x16x32_bf16(alf[mo], xhf, acc2[mo],0,0,0);
        }
      }
    }
  }

  #pragma unroll
  for(int mo=0;mo<2;mo++){
    #pragma unroll
    for(int reg=0;reg<4;reg++){
      int co = cog*64 + wm*32 + mo*16 + quad*4 + reg;
      float bsv = bias2[co];
      int r = r0 + (n>>3);
      int c = wn*8 + (n&7);
      size_t idx = (((size_t)b*128 + co)*16 + r)*16 + c;
      float mem = dm2[idx] + acc2[mo][reg] + bsv;
      float o = mem > 0.f ? mem : 0.f;
      dm2[idx] = (mem > 0.5f) ? 0.f : 0.3f*mem;
      float s = o;
      s += __shfl_xor(s, 8, 64);
      s += __shfl_xor(s, 1, 64);
      if((n & 9) == 0){
        int pr = pxg;
        int pc = wn*4 + ((n&7)>>1);
        size_t pidx = (((size_t)b*128 + co)*8 + pr)*8 + pc;
        float pm = dmp2[pidx] + s*0.25f;
        outp[pidx] = pm > 0.f ? pm : 0.f;
        dmp2[pidx]  = (pm > 0.5f) ? 0.f : 0.3f*pm;
      }
    }
  }
}

// ---------------- FC1 partial GEMM -> 32 slices ----------------
__global__ void __launch_bounds__(256)
k_fc1(const float* __restrict__ X, const float* __restrict__ Wf,
      float* __restrict__ u1s){
  __shared__ __align__(16) float lds[4896];
  float* Wl = lds;
  float* Xl = lds + 32*68;
  const int tid = threadIdx.x;
  int ot = blockIdx.x & 7, ks = blockIdx.x >> 3;
  int o0 = ot*32, k0 = ks*256;
  int w_id = tid >> 6, lane = tid & 63;
  int o_l = lane & 7, bg = lane >> 3;
  float acc[4][5];
  #pragma unroll
  for(int i=0;i<4;i++)
    #pragma unroll
    for(int j=0;j<5;j++) acc[i][j]=0.f;

  for(int c=0; c<4; c++){
    int kb = k0 + c*64;
    __syncthreads();
    for(int idx=tid; idx<512; idx+=256){
      int r = idx >> 4, j = idx & 15;
      *(float4*)&Wl[r*68 + j*4] = *(const float4*)&Wf[(size_t)(o0+r)*8192 + kb + j*4];
    }
    for(int idx=tid; idx<640; idx+=256){
      int r = idx >> 4, j = idx & 15;
      float4 v = make_float4(0.f,0.f,0.f,0.f);
      if(r < NB) v = *(const float4*)&X[(size_t)r*8192 + kb + j*4];
      *(float4*)&Xl[r*68 + j*4] = v;
    }
    __syncthreads();
    #pragma unroll
    for(int c4=0; c4<4; c4++){
      int g = w_id*4 + c4;
      float4 wv[4], xv[5];
      #pragma unroll
      for(int oi=0;oi<4;oi++) wv[oi] = *(const float4*)&Wl[(o_l+8*oi)*68 + g*4];
      #pragma unroll
      for(int bi=0;bi<5;bi++) xv[bi] = *(const float4*)&Xl[(bg*5+bi)*68 + g*4];
      #pragma unroll
      for(int oi=0;oi<4;oi++)
        #pragma unroll
        for(int bi=0;bi<5;bi++)
          acc[oi][bi] += wv[oi].x*xv[bi].x + wv[oi].y*xv[bi].y
                       + wv[oi].z*xv[bi].z + wv[oi].w*xv[bi].w;
    }
  }
  __syncthreads();
  if(w_id > 0){
    float* r = lds + ((w_id-1)*64 + lane)*20;
    #pragma unroll
    for(int oi=0;oi<4;oi++)
      #pragma unroll
      for(int bi=0;bi<5;bi++) r[oi*5+bi] = acc[oi][bi];
  }
  __syncthreads();
  if(w_id == 0){
    #pragma unroll
    for(int wv=0;wv<3;wv++){
      float* r = lds + (wv*64 + lane)*20;
      #pragma unroll
      for(int oi=0;oi<4;oi++)
        #pragma unroll
        for(int bi=0;bi<5;bi++) acc[oi][bi] += r[oi*5+bi];
    }
    #pragma unroll
    for(int bi=0;bi<5;bi++){
      int b = bg*5 + bi;
      if(b < NB){
        #pragma unroll
        for(int oi=0;oi<4;oi++)
          u1s[((size_t)ks*NB + b)*256 + o0 + o_l + 8*oi] = acc[oi][bi];
      }
    }
  }
}

// ---------------- FC2 standalone (final step only) ----------------
__global__ void __launch_bounds__(256)
k_fc2(const float* __restrict__ u1s, const float* __restrict__ bf1,
      const float* __restrict__ Wf2, const float* __restrict__ bf2,
      float* __restrict__ dmh1, float* __restrict__ dmh2, float* __restrict__ acc){
  __shared__ float xs[256];
  int b = blockIdx.x;
  int o = threadIdx.x;
  float u = bf1[o];
  const float* p = u1s + (size_t)b*256 + o;
  #pragma unroll
  for(int s=0;s<32;s++) u += p[(size_t)s*NB*256];
  int idx = b*256 + o;
  float mem = dmh1[idx] + u;
  float xo = mem > 0.f ? mem : 0.f;
  dmh1[idx] = (mem > 0.5f) ? 0.f : 0.3f*mem;
  xs[o] = xo;
  __syncthreads();
  int w_id = o >> 6, lane = o & 63;
  for(int oo=w_id; oo<11; oo+=4){
    const float* wr = Wf2 + oo*256;
    float s = xs[lane]*wr[lane] + xs[lane+64]*wr[lane+64]
            + xs[lane+128]*wr[lane+128] + xs[lane+192]*wr[lane+192];
    #pragma unroll
    for(int off=32; off>0; off>>=1) s += __shfl_down(s, off, 64);
    if(lane==0){
      int i2 = b*11 + oo;
      float m2 = dmh2[i2] + s + bf2[oo];
      float ov = m2 > 0.f ? m2 : 0.f;
      dmh2[i2] = (m2 > 0.5f) ? 0.f : 0.3f*m2;
      acc[i2] += ov * (1.0f/60.0f);
    }
  }
}

// ==================== launch ====================
extern "C" void kernel_launch(void* const* d_in, const int* in_sizes, int n_in,
                              void* d_out, int out_size, void* d_ws, size_t ws_size,
                              hipStream_t stream) {
  Params p;
  p.data = (const float*)d_in[0];
  p.W0  = (const float*)d_in[2];  p.b0  = (const float*)d_in[3];
  p.W1  = (const float*)d_in[4];  p.b1  = (const float*)d_in[5];
  p.W2  = (const float*)d_in[6];  p.b2  = (const float*)d_in[7];
  p.Wf1 = (const float*)d_in[8];  p.bf1 = (const float*)d_in[9];
  p.Wf2 = (const float*)d_in[10]; p.bf2 = (const float*)d_in[11];
  p.acc = (float*)d_out;

  float* ws = (float*)d_ws;
  const size_t S_XB    = (size_t)NT*NB*2*34*34;
  const size_t S_W0T   = 2*9*64;
  const size_t S_W1S   = 128*576/2;
  const size_t S_W2S   = 128*1152/2;
  const size_t S_XHL   = (size_t)NB*64*34*34;
  const size_t S_P1HL  = (size_t)NB*128*18*18;
  const size_t S_OP2   = (size_t)NB*128*8*8;
  const size_t S_U1S   = (size_t)32*NB*256;
  const size_t S_DM0   = (size_t)NB*64*34*34;
  const size_t S_DM1   = (size_t)NB*128*32*32;
  const size_t S_DMP1  = (size_t)NB*128*18*18;
  const size_t S_DM2   = (size_t)NB*128*16*16;
  const size_t S_DMP2  = S_OP2;
  const size_t S_OH1   = (size_t)NB*256;

  p.xb    = ws;  ws += S_XB;
  p.w0t   = ws;  ws += S_W0T;
  p.w1h   = (unsigned short*)ws;  ws += S_W1S;
  p.w1l   = (unsigned short*)ws;  ws += S_W1S;
  p.w2h   = (unsigned short*)ws;  ws += S_W2S;
  p.w2l   = (unsigned short*)ws;  ws += S_W2S;
  p.zbase = ws;
  p.xhl   = (unsigned int*)ws;    ws += S_XHL;
  p.p1hl  = (unsigned int*)ws;    ws += S_P1HL;
  p.outp2 = ws;  ws += S_OP2;
  p.u1s   = ws;  ws += S_U1S;
  p.dm0   = ws;  ws += S_DM0;
  p.dm1   = ws;  ws += S_DM1;
  p.dmp1  = ws;  ws += S_DMP1;
  p.dm2   = ws;  ws += S_DM2;
  p.dmp2  = ws;  ws += S_DMP2;
  p.dmh1  = ws;  ws += S_OH1;
  p.dmh2  = ws;  ws += (size_t)NB*11;
  p.zn4   = (int)((ws - p.zbase) / 4);

  k_prep<<<dim3(1024), dim3(256), 0, stream>>>(p);
  // prologue: conv0(0)
  k_conv0<2,64,32,8,4,8,2><<<dim3(288), dim3(256), 0, stream>>>(
      p.xb, p.w0t, p.b0, p.dm0, p.xhl);
  for(int t=0; t<NT; t++){
    // conv1(t): BK=64, 1152 blocks, 4 blocks/CU
    k_conv1<<<dim3(1152), dim3(256), 0, stream>>>(
        p.xhl, p.w1h, p.w1l, p.b1, p.dm1, p.dmp1, p.p1hl);
    // X2(t): conv2(t) BK=64 + conv0(t+1) + fc2(t-1) — 900 blocks
    const float* xnext = p.xb + (size_t)(t+1)*NB*2*34*34;
    k_x2<<<dim3(900), dim3(256), 0, stream>>>(
        p.p1hl, p.w2h, p.w2l, p.b2, p.dm2, p.dmp2, p.outp2,
        xnext, p.w0t, p.b0, p.dm0, p.xhl, t < NT-1 ? 1 : 0,
        p.u1s, p.bf1, p.Wf2, p.bf2, p.dmh1, p.dmh2, p.acc, t > 0 ? 1 : 0);
    // fc1(t): reads outp2(t) from X2(t)
    k_fc1<<<dim3(256), dim3(256), 0, stream>>>(p.outp2, p.Wf1, p.u1s);
  }
  // epilogue: fc2(59)
  k_fc2<<<dim3(36), dim3(256), 0, stream>>>(p.u1s, p.bf1, p.Wf2, p.bf2,
                                            p.dmh1, p.dmh2, p.acc);
}

// Round 17
// 5186.389 us; speedup vs baseline: 1.0164x; 1.0164x over previous
//
#include <hip/hip_runtime.h>

#define NB 36
#define NT 60

typedef __attribute__((ext_vector_type(8))) short short8;
typedef __attribute__((ext_vector_type(4))) float f32x4;

struct Params {
  const float *data;
  const float *W0, *b0, *W1, *b1, *W2, *b2, *Wf1, *bf1, *Wf2, *bf2;
  float *xb, *w0t;
  unsigned short *w1h, *w1l, *w2h, *w2l;
  unsigned int *xhl, *p1hl;
  float *outp2, *u1s;
  float *dm0, *dm1, *dmp1, *dm2, *dmp2, *dmh1, *dmh2;
  float *acc;
  float *zbase; int zn4;
};

__device__ __forceinline__ unsigned short bf16_rne(float v){
  unsigned int bits = __float_as_uint(v);
  unsigned int r = bits + 0x7FFFu + ((bits >> 16) & 1u);
  return (unsigned short)(r >> 16);
}
__device__ __forceinline__ unsigned int bf16pack(float v){
  unsigned short h = bf16_rne(v);
  float hf = __uint_as_float((unsigned int)h << 16);
  unsigned short l = bf16_rne(v - hf);
  return (unsigned int)h | ((unsigned int)l << 16);
}
__device__ __forceinline__ void unpack8(const unsigned int* q, short8& h8, short8& l8){
  unsigned int u[8];
  *(uint4*)&u[0] = *(const uint4*)q;
  *(uint4*)&u[4] = *(const uint4*)(q+4);
  #pragma unroll
  for(int i=0;i<8;i++){
    h8[i] = (short)(u[i] & 0xffffu);
    l8[i] = (short)(u[i] >> 16);
  }
}

// ---------------- prep ----------------
// xb fill: one (bc,pixel) per thread, t innermost (R13-verified: FETCH 179->10MB).
__global__ void __launch_bounds__(256) k_prep(Params p){
  int gt  = blockIdx.x*256 + threadIdx.x;
  int STR = gridDim.x*256;
  if(gt < NB*11) p.acc[gt] = 0.f;
  for(int i=gt; i<p.zn4; i+=STR) ((float4*)p.zbase)[i] = make_float4(0.f,0.f,0.f,0.f);
  const int PLANE = 34*34;
  for(int i=gt; i<NB*2*PLANE; i+=STR){
    int bc  = i / PLANE;
    int pix = i % PLANE;
    int ph = pix/34, pw = pix%34;
    float* xp = p.xb + (size_t)bc*PLANE + pix;
    if(ph>=1 && ph<=32 && pw>=1 && pw<=32){
      const float* dp = p.data + ((size_t)bc*1024 + (ph-1)*32 + (pw-1))*NT;
      for(int t=0;t<NT;t++)
        xp[(size_t)t*NB*2*PLANE] = (dp[t] > 1.0f) ? 1.0f : 0.0f;
    } else {
      for(int t=0;t<NT;t++)
        xp[(size_t)t*NB*2*PLANE] = 0.f;
    }
  }
  for(int i=gt; i<2*9*64; i+=STR){
    int co=i%64, rr=i/64; p.w0t[i] = p.W0[(co*2 + rr/9)*9 + rr%9];
  }
  // w1 split (RNE), layout [cout][k=cin*9+dd], K=576
  for(int i=gt; i<128*576; i+=STR){
    int co = i/576, k = i%576;
    int cin = k/9, dd = k%9;
    unsigned int pk = bf16pack(p.W1[(co*64+cin)*9 + dd]);
    p.w1h[i]=(unsigned short)(pk&0xffffu); p.w1l[i]=(unsigned short)(pk>>16);
  }
  // w2 split (RNE), layout [cout][k=cin*9+dd], K=1152
  for(int i=gt; i<128*1152; i+=STR){
    int co = i/1152, k = i%1152;
    int cin = k/9, dd = k%9;
    unsigned int pk = bf16pack(p.W2[(co*128+cin)*9 + dd]);
    p.w2h[i]=(unsigned short)(pk&0xffffu); p.w2l[i]=(unsigned short)(pk>>16);
  }
}

// ---------------- conv0 standalone (prologue t=0 only) ----------------
template<int Cin,int Cout,int HW,int CO,int PX,int TY,int CS>
__global__ void __launch_bounds__(HW*TY)
k_conv0(const float* __restrict__ x, const float* __restrict__ wt,
        const float* __restrict__ bias, float* __restrict__ dm,
        unsigned int* __restrict__ outhl)
{
  const int NCOG = Cout/CO;
  const int TH   = PX*TY;
  const int NHG  = HW/TH;
  const int NH4  = CO/4;
  const int NTHL = HW*TY;
  const int PIN  = HW+2;
  const int XR   = PX+2;
  int tile = blockIdx.x;
  int tid  = threadIdx.x;
  int cog = tile % NCOG;
  int hg  = (tile/NCOG) % NHG;
  int b   = tile/(NCOG*NHG);
  int w0  = tid % HW;
  int ty  = tid / HW;
  int h0  = hg*TH + ty*PX;

  __shared__ __align__(16) float wl[CS*9*CO];

  float accs[PX][CO];
  #pragma unroll
  for(int p=0;p<PX;p++)
    #pragma unroll
    for(int c=0;c<CO;c++) accs[p][c]=0.f;

  for(int cs=0; cs<Cin; cs+=CS){
    __syncthreads();
    for(int j=tid; j<CS*9*CO; j+=NTHL){
      int c  = j % CO;
      int rr = j / CO;
      wl[j] = wt[(cs*9 + rr)*Cout + cog*CO + c];
    }
    __syncthreads();

    for(int lc=0; lc<CS; lc++){
      const float* xc = x + ((size_t)b*Cin + cs + lc)*PIN*PIN + (size_t)h0*PIN + w0;
      float xv[XR][3];
      #pragma unroll
      for(int r=0;r<XR;r++)
        #pragma unroll
        for(int c=0;c<3;c++) xv[r][c] = xc[(size_t)r*PIN + c];
      const float4* w4 = (const float4*)(wl + lc*9*CO);
      #pragma unroll
      for(int dh=0;dh<3;dh++){
        #pragma unroll
        for(int g=0;g<NH4;g++){
          float4 wa = w4[(dh*3+0)*NH4+g];
          float4 wb = w4[(dh*3+1)*NH4+g];
          float4 wc = w4[(dh*3+2)*NH4+g];
          const float* A  = (const float*)&wa;
          const float* Bp = (const float*)&wb;
          const float* Cp = (const float*)&wc;
          #pragma unroll
          for(int cc=0;cc<4;cc++){
            #pragma unroll
            for(int px=0;px<PX;px++)
              accs[px][g*4+cc] += A[cc]*xv[px+dh][0] + Bp[cc]*xv[px+dh][1] + Cp[cc]*xv[px+dh][2];
          }
        }
      }
    }
  }

  int co0 = cog*CO;
  #pragma unroll
  for(int co=0; co<CO; co++){
    float bsv = bias[co0+co];
    const int OS = HW + 2;
    size_t plane = (size_t)(b*Cout + co0+co)*OS*OS;
    #pragma unroll
    for(int px=0; px<PX; px++){
      size_t idx = plane + (size_t)(h0+px+1)*OS + w0 + 1;
      float mem = dm[idx] + accs[px][co] + bsv;
      float ov = mem > 0.f ? mem : 0.f;
      dm[idx]  = (mem > 0.5f) ? 0.f : 0.3f*mem;
      outhl[idx] = bf16pack(ov);
    }
  }
}

// ---------------- conv1: implicit-GEMM MFMA bf16x3 + LIAF + pool -> packed bf16 ----------------
// R14-verified: BK=64 (9 double-chunks, 18 barriers). LDS 37.9KB, VGPR 52, 4 blocks/CU.
__global__ void __launch_bounds__(256, 4)
k_conv1(const unsigned int* __restrict__ xhl,
        const unsigned short* __restrict__ w1h, const unsigned short* __restrict__ w1l,
        const float* __restrict__ bias, float* __restrict__ dm,
        float* __restrict__ dmp, unsigned int* __restrict__ p1hl)
{
  __shared__ __align__(16) unsigned int ldsu[9472];    // 37.9 KB
  unsigned short* Ah = (unsigned short*)ldsu;          // 64*72 ushorts
  unsigned short* Al = (unsigned short*)(ldsu + 2304);
  unsigned int*   Xp = ldsu + 4608;                    // 64*76 uints

  int bid = blockIdx.x;
  int cog = bid & 1;
  int pxg = (bid>>1) & 15;
  int b   = bid >> 5;
  int tid = threadIdx.x;
  int wv  = tid >> 6, lane = tid & 63;
  int wm = wv & 1, wn = wv >> 1;
  int n = lane & 15, quad = lane >> 4;
  int r0 = pxg*2;

  f32x4 acc[2][2];
  #pragma unroll
  for(int mo=0;mo<2;mo++)
    #pragma unroll
    for(int no=0;no<2;no++) acc[mo][no] = (f32x4){0.f,0.f,0.f,0.f};

  int aco = tid >> 2;
  int aq  = tid & 3;
  const unsigned short* whp = w1h + (size_t)(cog*64 + aco)*576 + aq*8;
  const unsigned short* wlp = w1l + (size_t)(cog*64 + aco)*576 + aq*8;
  int sk  = tid >> 3;
  int pxq = tid & 7;
  int srow = pxq >> 2;
  int scol = (pxq & 3) * 8;
  int rA   = pxq * 8;
  int skx  = sk ^ (((pxq >> 1) & 3) << 3);

  // ---- prologue: prefetch chunk 0, both k-halves (contiguous -> dwordx4) ----
  uint4 whaA = *(const uint4*)(whp);
  uint4 whaB = *(const uint4*)(whp + 32);
  uint4 wlaA = *(const uint4*)(wlp);
  uint4 wlaB = *(const uint4*)(wlp + 32);
  unsigned int tmp[16];
  {
    int kg0 = sk,      cin0 = kg0/9, dd0 = kg0 - cin0*9, dh0 = dd0/3, dw0 = dd0 - dh0*3;
    int kg1 = sk + 32, cin1 = kg1/9, dd1 = kg1 - cin1*9, dh1 = dd1/3, dw1 = dd1 - dh1*3;
    const unsigned int* s0 = xhl + ((size_t)(b*64 + cin0)*34 + (r0 + srow + dh0))*34 + scol + dw0;
    const unsigned int* s1 = xhl + ((size_t)(b*64 + cin1)*34 + (r0 + srow + dh1))*34 + scol + dw1;
    #pragma unroll
    for(int i=0;i<8;i++){ tmp[i] = s0[i]; tmp[8+i] = s1[i]; }
  }

  for(int ch=0; ch<9; ch++){
    __syncthreads();
    *(uint4*)&Ah[aco*72 + aq*8]      = whaA;
    *(uint4*)&Ah[aco*72 + aq*8 + 32] = whaB;
    *(uint4*)&Al[aco*72 + aq*8]      = wlaA;
    *(uint4*)&Al[aco*72 + aq*8 + 32] = wlaB;
    #pragma unroll
    for(int i=0;i<8;i++){
      Xp[(rA+i)*76 + skx]      = tmp[i];
      Xp[(rA+i)*76 + skx + 32] = tmp[8+i];
    }
    __syncthreads();

    // ---- prefetch next double-chunk during compute ----
    if(ch+1 < 9){
      int k0n = (ch+1)*64;
      whaA = *(const uint4*)(whp + k0n);
      whaB = *(const uint4*)(whp + k0n + 32);
      wlaA = *(const uint4*)(wlp + k0n);
      wlaB = *(const uint4*)(wlp + k0n + 32);
      int kg0 = k0n + sk,      cin0 = kg0/9, dd0 = kg0 - cin0*9, dh0 = dd0/3, dw0 = dd0 - dh0*3;
      int kg1 = k0n + sk + 32, cin1 = kg1/9, dd1 = kg1 - cin1*9, dh1 = dd1/3, dw1 = dd1 - dh1*3;
      const unsigned int* s0 = xhl + ((size_t)(b*64 + cin0)*34 + (r0 + srow + dh0))*34 + scol + dw0;
      const unsigned int* s1 = xhl + ((size_t)(b*64 + cin1)*34 + (r0 + srow + dh1))*34 + scol + dw1;
      #pragma unroll
      for(int i=0;i<8;i++){ tmp[i] = s0[i]; tmp[8+i] = s1[i]; }
    }

    #pragma unroll
    for(int kk=0; kk<2; kk++){
      int ko = kk*32;
      short8 ahf[2], alf[2];
      #pragma unroll
      for(int mo=0;mo<2;mo++){
        int row = wm*32 + mo*16 + n;
        ahf[mo] = *(const short8*)&Ah[row*72 + ko + quad*8];
        alf[mo] = *(const short8*)&Al[row*72 + ko + quad*8];
      }
      #pragma unroll
      for(int no=0;no<2;no++){
        int prow = no*32 + wn*16 + n;
        int cb = ((quad ^ (no*2 + wn)) & 3) * 8;
        short8 xhf, xlf;
        unpack8(&Xp[prow*76 + ko + cb], xhf, xlf);
        #pragma unroll
        for(int mo=0;mo<2;mo++){
          acc[mo][no] = __builtin_amdgcn_mfma_f32_16x16x32_bf16(ahf[mo], xhf, acc[mo][no],0,0,0);
          acc[mo][no] = __builtin_amdgcn_mfma_f32_16x16x32_bf16(ahf[mo], xlf, acc[mo][no],0,0,0);
          acc[mo][no] = __builtin_amdgcn_mfma_f32_16x16x32_bf16(alf[mo], xhf, acc[mo][no],0,0,0);
        }
      }
    }
  }

  // epilogue: LIAF (dm1 32x32) + 2x2 pool -> packed bf16 (18x18 padded)
  #pragma unroll
  for(int mo=0;mo<2;mo++){
    #pragma unroll
    for(int reg=0;reg<4;reg++){
      int co = cog*64 + wm*32 + mo*16 + quad*4 + reg;
      float bsv = bias[co];
      float o[2];
      #pragma unroll
      for(int no=0;no<2;no++){
        int r = r0 + no;
        int c = wn*16 + n;
        size_t idx = (((size_t)b*128 + co)*32 + r)*32 + c;
        float mem = dm[idx] + acc[mo][no][reg] + bsv;
        o[no] = mem > 0.f ? mem : 0.f;
        dm[idx] = (mem > 0.5f) ? 0.f : 0.3f*mem;
      }
      float s = o[0] + o[1];
      s += __shfl_xor(s, 1, 64);
      if((n&1)==0){
        int pr = pxg;
        int pc = wn*8 + (n>>1);
        size_t pidx = (((size_t)b*128 + co)*18 + pr+1)*18 + pc+1;
        float pm = dmp[pidx] + s*0.25f;
        float pv = pm > 0.f ? pm : 0.f;
        dmp[pidx] = (pm > 0.5f) ? 0.f : 0.3f*pm;
        p1hl[pidx] = bf16pack(pv);
      }
    }
  }
}

// ---------------- X2: conv2(t) [0..575] + conv0(t+1) [576..863] + fc2(t-1) [864..899] ----
// R10/R14-verified (VGPR=64, LDS 15.9KB). conv2 stays BK=32 — R15 showed BK=64 here is
// net-negative (LDS growth eats the barrier saving in the fused kernel).
__global__ void __launch_bounds__(256, 4)
k_x2(const unsigned int* __restrict__ p1hl,
     const unsigned short* __restrict__ w2h, const unsigned short* __restrict__ w2l,
     const float* __restrict__ bias2, float* __restrict__ dm2,
     float* __restrict__ dmp2, float* __restrict__ outp,
     const float* __restrict__ xnext, const float* __restrict__ w0t,
     const float* __restrict__ bias0, float* __restrict__ dm0,
     unsigned int* __restrict__ xhl, int do_c0,
     const float* __restrict__ u1s, const float* __restrict__ bf1,
     const float* __restrict__ Wf2, const float* __restrict__ bf2,
     float* __restrict__ dmh1, float* __restrict__ dmh2,
     float* __restrict__ accv, int do_fc2)
{
  __shared__ __align__(16) unsigned int ldsu[3968];
  const int tid = threadIdx.x;
  int bid = blockIdx.x;

  if(bid >= 864){
    // ---------- fc2(t-1) ----------
    if(!do_fc2) return;
    float* xs = (float*)ldsu;
    int b = bid - 864;
    int o = tid;
    float u = bf1[o];
    const float* pu = u1s + (size_t)b*256 + o;
    #pragma unroll
    for(int s=0;s<32;s++) u += pu[(size_t)s*NB*256];
    int idx = b*256 + o;
    float mem = dmh1[idx] + u;
    float xo = mem > 0.f ? mem : 0.f;
    dmh1[idx] = (mem > 0.5f) ? 0.f : 0.3f*mem;
    xs[o] = xo;
    __syncthreads();
    int w_id = o >> 6, ln = o & 63;
    for(int oo=w_id; oo<11; oo+=4){
      const float* wr = Wf2 + oo*256;
      float s = xs[ln]*wr[ln] + xs[ln+64]*wr[ln+64]
              + xs[ln+128]*wr[ln+128] + xs[ln+192]*wr[ln+192];
      #pragma unroll
      for(int off=32; off>0; off>>=1) s += __shfl_down(s, off, 64);
      if(ln==0){
        int i2 = b*11 + oo;
        float m2 = dmh2[i2] + s + bf2[oo];
        float ov = m2 > 0.f ? m2 : 0.f;
        dmh2[i2] = (m2 > 0.5f) ? 0.f : 0.3f*m2;
        accv[i2] += ov * (1.0f/60.0f);
      }
    }
    return;
  }

  if(bid >= 576){
    // ---------- conv0(t+1) ----------
    if(!do_c0) return;
    float* wl = (float*)ldsu;      // 144 floats
    int tile = bid - 576;
    int cog = tile & 7;
    int b   = tile >> 3;
    int w0  = tid & 31;
    int ty  = tid >> 5;
    int h0  = ty*4;

    float accs[4][8];
    #pragma unroll
    for(int p=0;p<4;p++)
      #pragma unroll
      for(int c=0;c<8;c++) accs[p][c]=0.f;

    if(tid < 144){
      int c  = tid % 8;
      int rr = tid / 8;
      wl[tid] = w0t[rr*64 + cog*8 + c];
    }
    __syncthreads();

    #pragma unroll
    for(int lc=0; lc<2; lc++){
      const float* xc = xnext + ((size_t)b*2 + lc)*34*34 + (size_t)h0*34 + w0;
      float xv[6][3];
      #pragma unroll
      for(int r=0;r<6;r++)
        #pragma unroll
        for(int c=0;c<3;c++) xv[r][c] = xc[(size_t)r*34 + c];
      const float4* w4 = (const float4*)(wl + lc*72);
      #pragma unroll
      for(int dh=0;dh<3;dh++){
        #pragma unroll
        for(int g=0;g<2;g++){
          float4 wa = w4[(dh*3+0)*2+g];
          float4 wb = w4[(dh*3+1)*2+g];
          float4 wc = w4[(dh*3+2)*2+g];
          const float* A  = (const float*)&wa;
          const float* Bp = (const float*)&wb;
          const float* Cp = (const float*)&wc;
          #pragma unroll
          for(int cc=0;cc<4;cc++){
            #pragma unroll
            for(int px=0;px<4;px++)
              accs[px][g*4+cc] += A[cc]*xv[px+dh][0] + Bp[cc]*xv[px+dh][1] + Cp[cc]*xv[px+dh][2];
          }
        }
      }
    }

    int co0 = cog*8;
    #pragma unroll
    for(int co=0; co<8; co++){
      float bsv = bias0[co0+co];
      size_t plane = (size_t)(b*64 + co0+co)*34*34;
      #pragma unroll
      for(int px=0; px<4; px++){
        size_t idx = plane + (size_t)(h0+px+1)*34 + w0 + 1;
        float mem = dm0[idx] + accs[px][co] + bsv;
        float ov = mem > 0.f ? mem : 0.f;
        dm0[idx]  = (mem > 0.5f) ? 0.f : 0.3f*mem;
        xhl[idx] = bf16pack(ov);
      }
    }
    return;
  }

  // ---------- conv2(t) ----------
  unsigned short* Ah = (unsigned short*)ldsu;          // 64*40
  unsigned short* Al = (unsigned short*)(ldsu + 1280);
  unsigned int*   Xp = ldsu + 2560;                    // 32*44 uints

  int cog = bid & 1;
  int pxg = (bid>>1) & 7;
  int b   = bid >> 4;
  int wv  = tid >> 6, lane = tid & 63;
  int wm = wv & 1, wn = wv >> 1;
  int n = lane & 15, quad = lane >> 4;
  int r0 = pxg*2;

  f32x4 acc2[2];
  #pragma unroll
  for(int mo=0;mo<2;mo++) acc2[mo] = (f32x4){0.f,0.f,0.f,0.f};

  int aco = tid >> 2;
  int aq  = tid & 3;
  const unsigned short* whp = w2h + (size_t)(cog*64 + aco)*1152 + aq*8;
  const unsigned short* wlp = w2l + (size_t)(cog*64 + aco)*1152 + aq*8;
  int sk  = tid >> 3;
  int pxq = tid & 7;
  int srow = pxq >> 2;
  int scol = (pxq & 3) * 4;
  int rA   = pxq * 4;
  int skx  = sk ^ ((pxq >> 2) << 3);

  uint4 wha = *(const uint4*)(whp);
  uint4 wla = *(const uint4*)(wlp);
  unsigned int tmp[4];
  {
    int cin = sk / 9;
    int dd  = sk - cin*9;
    int dh = dd/3, dw = dd - dh*3;
    const unsigned int* sx = p1hl + ((size_t)(b*128 + cin)*18 + (r0 + srow + dh))*18 + scol + dw;
    #pragma unroll
    for(int i=0;i<4;i++) tmp[i] = sx[i];
  }

  for(int ch=0; ch<36; ch++){
    __syncthreads();
    *(uint4*)&Ah[aco*40 + aq*8] = wha;
    *(uint4*)&Al[aco*40 + aq*8] = wla;
    #pragma unroll
    for(int i=0;i<4;i++) Xp[(rA+i)*44 + skx] = tmp[i];
    __syncthreads();

    if(ch+1 < 36){
      int k0n = (ch+1)*32;
      wha = *(const uint4*)(whp + k0n);
      wla = *(const uint4*)(wlp + k0n);
      int kg = k0n + sk;
      int cin = kg / 9;
      int dd  = kg - cin*9;
      int dh = dd/3, dw = dd - dh*3;
      const unsigned int* sx = p1hl + ((size_t)(b*128 + cin)*18 + (r0 + srow + dh))*18 + scol + dw;
      #pragma unroll
      for(int i=0;i<4;i++) tmp[i] = sx[i];
    }

    short8 ahf[2], alf[2];
    #pragma unroll
    for(int mo=0;mo<2;mo++){
      int row = wm*32 + mo*16 + n;
      ahf[mo] = *(const short8*)&Ah[row*40 + quad*8];
      alf[mo] = *(const short8*)&Al[row*40 + quad*8];
    }
    {
      int prow = (n>>3)*16 + wn*8 + (n&7);
      int cb = ((quad ^ (n>>3)) & 3) * 8;
      short8 xhf, xlf;
      unpack8(&Xp[prow*44 + cb], xhf, xlf);
      #pragma unroll
      for(int mo=0;mo<2;mo++){
        acc2[mo] = __builtin_amdgcn_mfma_f32_16x16x32_bf16(ahf[mo], xhf, acc2[mo],0,0,0);
        acc2[mo] = __builtin_amdgcn_mfma_f32_16x16x32_bf16(ahf[mo], xlf, acc2[mo],0,0,0);
        acc2[mo] = __builtin_amdgcn_mfma_f32_16x16x32_bf16(alf[mo], xhf, acc2[mo],0,0,0);
      }
    }
  }

  #pragma unroll
  for(int mo=0;mo<2;mo++){
    #pragma unroll
    for(int reg=0;reg<4;reg++){
      int co = cog*64 + wm*32 + mo*16 + quad*4 + reg;
      float bsv = bias2[co];
      int r = r0 + (n>>3);
      int c = wn*8 + (n&7);
      size_t idx = (((size_t)b*128 + co)*16 + r)*16 + c;
      float mem = dm2[idx] + acc2[mo][reg] + bsv;
      float o = mem > 0.f ? mem : 0.f;
      dm2[idx] = (mem > 0.5f) ? 0.f : 0.3f*mem;
      float s = o;
      s += __shfl_xor(s, 8, 64);
      s += __shfl_xor(s, 1, 64);
      if((n & 9) == 0){
        int pr = pxg;
        int pc = wn*4 + ((n&7)>>1);
        size_t pidx = (((size_t)b*128 + co)*8 + pr)*8 + pc;
        float pm = dmp2[pidx] + s*0.25f;
        outp[pidx] = pm > 0.f ? pm : 0.f;
        dmp2[pidx]  = (pm > 0.5f) ? 0.f : 0.3f*pm;
      }
    }
  }
}

// ---------------- FC1 partial GEMM -> 32 slices ----------------
__global__ void __launch_bounds__(256)
k_fc1(const float* __restrict__ X, const float* __restrict__ Wf,
      float* __restrict__ u1s){
  __shared__ __align__(16) float lds[4896];
  float* Wl = lds;
  float* Xl = lds + 32*68;
  const int tid = threadIdx.x;
  int ot = blockIdx.x & 7, ks = blockIdx.x >> 3;
  int o0 = ot*32, k0 = ks*256;
  int w_id = tid >> 6, lane = tid & 63;
  int o_l = lane & 7, bg = lane >> 3;
  float acc[4][5];
  #pragma unroll
  for(int i=0;i<4;i++)
    #pragma unroll
    for(int j=0;j<5;j++) acc[i][j]=0.f;

  for(int c=0; c<4; c++){
    int kb = k0 + c*64;
    __syncthreads();
    for(int idx=tid; idx<512; idx+=256){
      int r = idx >> 4, j = idx & 15;
      *(float4*)&Wl[r*68 + j*4] = *(const float4*)&Wf[(size_t)(o0+r)*8192 + kb + j*4];
    }
    for(int idx=tid; idx<640; idx+=256){
      int r = idx >> 4, j = idx & 15;
      float4 v = make_float4(0.f,0.f,0.f,0.f);
      if(r < NB) v = *(const float4*)&X[(size_t)r*8192 + kb + j*4];
      *(float4*)&Xl[r*68 + j*4] = v;
    }
    __syncthreads();
    #pragma unroll
    for(int c4=0; c4<4; c4++){
      int g = w_id*4 + c4;
      float4 wv[4], xv[5];
      #pragma unroll
      for(int oi=0;oi<4;oi++) wv[oi] = *(const float4*)&Wl[(o_l+8*oi)*68 + g*4];
      #pragma unroll
      for(int bi=0;bi<5;bi++) xv[bi] = *(const float4*)&Xl[(bg*5+bi)*68 + g*4];
      #pragma unroll
      for(int oi=0;oi<4;oi++)
        #pragma unroll
        for(int bi=0;bi<5;bi++)
          acc[oi][bi] += wv[oi].x*xv[bi].x + wv[oi].y*xv[bi].y
                       + wv[oi].z*xv[bi].z + wv[oi].w*xv[bi].w;
    }
  }
  __syncthreads();
  if(w_id > 0){
    float* r = lds + ((w_id-1)*64 + lane)*20;
    #pragma unroll
    for(int oi=0;oi<4;oi++)
      #pragma unroll
      for(int bi=0;bi<5;bi++) r[oi*5+bi] = acc[oi][bi];
  }
  __syncthreads();
  if(w_id == 0){
    #pragma unroll
    for(int wv=0;wv<3;wv++){
      float* r = lds + (wv*64 + lane)*20;
      #pragma unroll
      for(int oi=0;oi<4;oi++)
        #pragma unroll
        for(int bi=0;bi<5;bi++) acc[oi][bi] += r[oi*5+bi];
    }
    #pragma unroll
    for(int bi=0;bi<5;bi++){
      int b = bg*5 + bi;
      if(b < NB){
        #pragma unroll
        for(int oi=0;oi<4;oi++)
          u1s[((size_t)ks*NB + b)*256 + o0 + o_l + 8*oi] = acc[oi][bi];
      }
    }
  }
}

// ---------------- FC2 standalone (final step only) ----------------
__global__ void __launch_bounds__(256)
k_fc2(const float* __restrict__ u1s, const float* __restrict__ bf1,
      const float* __restrict__ Wf2, const float* __restrict__ bf2,
      float* __restrict__ dmh1, float* __restrict__ dmh2, float* __restrict__ acc){
  __shared__ float xs[256];
  int b = blockIdx.x;
  int o = threadIdx.x;
  float u = bf1[o];
  const float* p = u1s + (size_t)b*256 + o;
  #pragma unroll
  for(int s=0;s<32;s++) u += p[(size_t)s*NB*256];
  int idx = b*256 + o;
  float mem = dmh1[idx] + u;
  float xo = mem > 0.f ? mem : 0.f;
  dmh1[idx] = (mem > 0.5f) ? 0.f : 0.3f*mem;
  xs[o] = xo;
  __syncthreads();
  int w_id = o >> 6, lane = o & 63;
  for(int oo=w_id; oo<11; oo+=4){
    const float* wr = Wf2 + oo*256;
    float s = xs[lane]*wr[lane] + xs[lane+64]*wr[lane+64]
            + xs[lane+128]*wr[lane+128] + xs[lane+192]*wr[lane+192];
    #pragma unroll
    for(int off=32; off>0; off>>=1) s += __shfl_down(s, off, 64);
    if(lane==0){
      int i2 = b*11 + oo;
      float m2 = dmh2[i2] + s + bf2[oo];
      float ov = m2 > 0.f ? m2 : 0.f;
      dmh2[i2] = (m2 > 0.5f) ? 0.f : 0.3f*m2;
      acc[i2] += ov * (1.0f/60.0f);
    }
  }
}

// ==================== launch ====================
extern "C" void kernel_launch(void* const* d_in, const int* in_sizes, int n_in,
                              void* d_out, int out_size, void* d_ws, size_t ws_size,
                              hipStream_t stream) {
  Params p;
  p.data = (const float*)d_in[0];
  p.W0  = (const float*)d_in[2];  p.b0  = (const float*)d_in[3];
  p.W1  = (const float*)d_in[4];  p.b1  = (const float*)d_in[5];
  p.W2  = (const float*)d_in[6];  p.b2  = (const float*)d_in[7];
  p.Wf1 = (const float*)d_in[8];  p.bf1 = (const float*)d_in[9];
  p.Wf2 = (const float*)d_in[10]; p.bf2 = (const float*)d_in[11];
  p.acc = (float*)d_out;

  float* ws = (float*)d_ws;
  const size_t S_XB    = (size_t)NT*NB*2*34*34;
  const size_t S_W0T   = 2*9*64;
  const size_t S_W1S   = 128*576/2;
  const size_t S_W2S   = 128*1152/2;
  const size_t S_XHL   = (size_t)NB*64*34*34;
  const size_t S_P1HL  = (size_t)NB*128*18*18;
  const size_t S_OP2   = (size_t)NB*128*8*8;
  const size_t S_U1S   = (size_t)32*NB*256;
  const size_t S_DM0   = (size_t)NB*64*34*34;
  const size_t S_DM1   = (size_t)NB*128*32*32;
  const size_t S_DMP1  = (size_t)NB*128*18*18;
  const size_t S_DM2   = (size_t)NB*128*16*16;
  const size_t S_DMP2  = S_OP2;
  const size_t S_OH1   = (size_t)NB*256;

  p.xb    = ws;  ws += S_XB;
  p.w0t   = ws;  ws += S_W0T;
  p.w1h   = (unsigned short*)ws;  ws += S_W1S;
  p.w1l   = (unsigned short*)ws;  ws += S_W1S;
  p.w2h   = (unsigned short*)ws;  ws += S_W2S;
  p.w2l   = (unsigned short*)ws;  ws += S_W2S;
  p.zbase = ws;
  p.xhl   = (unsigned int*)ws;    ws += S_XHL;
  p.p1hl  = (unsigned int*)ws;    ws += S_P1HL;
  p.outp2 = ws;  ws += S_OP2;
  p.u1s   = ws;  ws += S_U1S;
  p.dm0   = ws;  ws += S_DM0;
  p.dm1   = ws;  ws += S_DM1;
  p.dmp1  = ws;  ws += S_DMP1;
  p.dm2   = ws;  ws += S_DM2;
  p.dmp2  = ws;  ws += S_DMP2;
  p.dmh1  = ws;  ws += S_OH1;
  p.dmh2  = ws;  ws += (size_t)NB*11;
  p.zn4   = (int)((ws - p.zbase) / 4);

  k_prep<<<dim3(1024), dim3(256), 0, stream>>>(p);
  // prologue: conv0(0)
  k_conv0<2,64,32,8,4,8,2><<<dim3(288), dim3(256), 0, stream>>>(
      p.xb, p.w0t, p.b0, p.dm0, p.xhl);
  for(int t=0; t<NT; t++){
    // conv1(t): BK=64, 1152 blocks, 4 blocks/CU
    k_conv1<<<dim3(1152), dim3(256), 0, stream>>>(
        p.xhl, p.w1h, p.w1l, p.b1, p.dm1, p.dmp1, p.p1hl);
    // X2(t): conv2(t) + conv0(t+1) + fc2(t-1) — 900 blocks
    const float* xnext = p.xb + (size_t)(t+1)*NB*2*34*34;
    k_x2<<<dim3(900), dim3(256), 0, stream>>>(
        p.p1hl, p.w2h, p.w2l, p.b2, p.dm2, p.dmp2, p.outp2,
        xnext, p.w0t, p.b0, p.dm0, p.xhl, t < NT-1 ? 1 : 0,
        p.u1s, p.bf1, p.Wf2, p.bf2, p.dmh1, p.dmh2, p.acc, t > 0 ? 1 : 0);
    // fc1(t): reads outp2(t) from X2(t)
    k_fc1<<<dim3(256), dim3(256), 0, stream>>>(p.outp2, p.Wf1, p.u1s);
  }
  // epilogue: fc2(59)
  k_fc2<<<dim3(36), dim3(256), 0, stream>>>(p.u1s, p.bf1, p.Wf2, p.bf2,
                                            p.dmh1, p.dmh2, p.acc);
}